// Round 1
// baseline (624.638 us; speedup 1.0000x reference)
//
#include <hip/hip_runtime.h>
#include <math.h>

#define NNODES 100000

// ---------- CSR build ----------

__global__ __launch_bounds__(256) void k_hist(const int* __restrict__ dst, int* __restrict__ cnt, int E) {
    int i = blockIdx.x * blockDim.x + threadIdx.x;
    int stride = gridDim.x * blockDim.x;
    for (; i < E; i += stride) atomicAdd(&cnt[dst[i]], 1);
}

__global__ __launch_bounds__(1024) void k_scan1(const int* __restrict__ cnt, int* __restrict__ rowptr,
                                                int* __restrict__ bsum, int N) {
    __shared__ int s[1024];
    int t = threadIdx.x;
    int i = blockIdx.x * 1024 + t;
    int v = (i < N) ? cnt[i] : 0;
    s[t] = v;
    __syncthreads();
    #pragma unroll
    for (int off = 1; off < 1024; off <<= 1) {
        int u = (t >= off) ? s[t - off] : 0;
        __syncthreads();
        s[t] += u;
        __syncthreads();
    }
    if (i < N) rowptr[i] = s[t] - v;   // local exclusive prefix
    if (t == 1023) bsum[blockIdx.x] = s[1023];
}

__global__ __launch_bounds__(128) void k_scan2(const int* __restrict__ bsum, int* __restrict__ boffs,
                                               int* __restrict__ rowptr, int nb, int N) {
    __shared__ int s[128];
    int t = threadIdx.x;
    int v = (t < nb) ? bsum[t] : 0;
    s[t] = v;
    __syncthreads();
    #pragma unroll
    for (int off = 1; off < 128; off <<= 1) {
        int u = (t >= off) ? s[t - off] : 0;
        __syncthreads();
        s[t] += u;
        __syncthreads();
    }
    if (t < nb) boffs[t] = s[t] - v;   // exclusive block offsets
    if (t == 127) rowptr[N] = s[127];  // total = E
}

__global__ __launch_bounds__(1024) void k_scan3(const int* __restrict__ cnt, int* __restrict__ rowptr,
                                                const int* __restrict__ boffs, int* __restrict__ cur,
                                                float* __restrict__ dinv, int N) {
    int i = blockIdx.x * 1024 + threadIdx.x;
    if (i >= N) return;
    int val = rowptr[i] + boffs[blockIdx.x];
    rowptr[i] = val;
    cur[i] = val;
    dinv[i] = 1.0f / sqrtf((float)(cnt[i] + 1));  // self-loop included; deg >= 1 always
}

__global__ __launch_bounds__(256) void k_scatter(const int* __restrict__ src, const int* __restrict__ dst,
                                                 int* __restrict__ cur, int* __restrict__ ssort, int E) {
    int i = blockIdx.x * blockDim.x + threadIdx.x;
    int stride = gridDim.x * blockDim.x;
    for (; i < E; i += stride) {
        int pos = atomicAdd(&cur[dst[i]], 1);
        ssort[pos] = src[i];
    }
}

// ---------- G = dinv[i] * (X @ W) ----------
// wave-per-node: lane c holds W[:,c] in 64 VGPRs, x row read as uniform float4 broadcasts
__global__ __launch_bounds__(256) void k_transform(const float* __restrict__ X, const float* __restrict__ W,
                                                   const float* __restrict__ dinv, float* __restrict__ G, int N) {
    int lane = threadIdx.x & 63;
    int wid = threadIdx.x >> 6;
    float w[64];
    #pragma unroll
    for (int k = 0; k < 64; k++) w[k] = W[k * 64 + lane];
    int wave = blockIdx.x * 4 + wid;
    int nw = gridDim.x * 4;
    for (int i = wave; i < N; i += nw) {
        const float4* xr = (const float4*)(X + (size_t)i * 64);
        float acc = 0.f;
        #pragma unroll
        for (int kk = 0; kk < 16; kk++) {
            float4 x4 = xr[kk];
            acc = fmaf(x4.x, w[4 * kk + 0], acc);
            acc = fmaf(x4.y, w[4 * kk + 1], acc);
            acc = fmaf(x4.z, w[4 * kk + 2], acc);
            acc = fmaf(x4.w, w[4 * kk + 3], acc);
        }
        G[(size_t)i * 64 + lane] = acc * dinv[i];
    }
}

// ---------- out = relu(dinv[i] * (G[i] + sum_{j in N(i)} G[j]) + b) ----------
__global__ __launch_bounds__(256) void k_agg(const float* __restrict__ G, const int* __restrict__ rowptr,
                                             const int* __restrict__ ssort, const float* __restrict__ dinv,
                                             const float* __restrict__ bias, float* __restrict__ O, int N) {
    int lane = threadIdx.x & 63;
    int wid = threadIdx.x >> 6;
    int i = blockIdx.x * 4 + wid;
    if (i >= N) return;
    float acc = G[(size_t)i * 64 + lane];  // self-loop term (dinv folded into G)
    int beg = rowptr[i], end = rowptr[i + 1];
    for (int e = beg; e < end; e++) {
        int s2 = ssort[e];
        acc += G[(size_t)s2 * 64 + lane];
    }
    float r = fmaf(dinv[i], acc, bias[lane]);
    O[(size_t)i * 64 + lane] = fmaxf(r, 0.f);
}

// ---------- softmax(H @ Wfc + bfc) ----------
__global__ __launch_bounds__(256) void k_fc_softmax(const float* __restrict__ H, const float* __restrict__ Wfc,
                                                    const float* __restrict__ bfc, float* __restrict__ O, int N) {
    __shared__ float wf[64 * 16];
    __shared__ float bf[16];
    int t = threadIdx.x;
    for (int k = t; k < 1024; k += 256) wf[k] = Wfc[k];
    if (t < 16) bf[t] = bfc[t];
    __syncthreads();
    int gid = blockIdx.x * 256 + t;
    int node = gid >> 4;
    int c = gid & 15;
    if (node >= N) return;
    const float4* hv = (const float4*)(H + (size_t)node * 64);
    float acc = bf[c];
    #pragma unroll
    for (int kk = 0; kk < 16; kk++) {
        float4 h4 = hv[kk];
        acc = fmaf(h4.x, wf[(4 * kk + 0) * 16 + c], acc);
        acc = fmaf(h4.y, wf[(4 * kk + 1) * 16 + c], acc);
        acc = fmaf(h4.z, wf[(4 * kk + 2) * 16 + c], acc);
        acc = fmaf(h4.w, wf[(4 * kk + 3) * 16 + c], acc);
    }
    float m = acc;
    #pragma unroll
    for (int mask = 1; mask < 16; mask <<= 1) m = fmaxf(m, __shfl_xor(m, mask));
    float ex = expf(acc - m);
    float s = ex;
    #pragma unroll
    for (int mask = 1; mask < 16; mask <<= 1) s += __shfl_xor(s, mask);
    O[(size_t)node * 16 + c] = ex / s;
}

extern "C" void kernel_launch(void* const* d_in, const int* in_sizes, int n_in,
                              void* d_out, int out_size, void* d_ws, size_t ws_size,
                              hipStream_t stream) {
    const float* x   = (const float*)d_in[0];
    const int*   ei  = (const int*)d_in[1];
    const float* W1  = (const float*)d_in[2];
    const float* b1  = (const float*)d_in[3];
    const float* W2  = (const float*)d_in[4];
    const float* b2  = (const float*)d_in[5];
    const float* Wfc = (const float*)d_in[6];
    const float* bfc = (const float*)d_in[7];
    float* out = (float*)d_out;
    const int N = NNODES;
    const int E = in_sizes[1] / 2;
    const int NB = (N + 1023) / 1024;  // 98

    char* ws = (char*)d_ws;
    size_t off = 0;
    auto take = [&](size_t bytes) {
        char* p = ws + off;
        off = (off + bytes + 255) & ~(size_t)255;
        return p;
    };
    int*   cnt    = (int*)take((size_t)N * 4);
    int*   rowptr = (int*)take((size_t)(N + 1) * 4);
    int*   cur    = (int*)take((size_t)N * 4);
    int*   ssort  = (int*)take((size_t)E * 4);
    float* dinv   = (float*)take((size_t)N * 4);
    int*   bsum   = (int*)take((size_t)NB * 4);
    int*   boffs  = (int*)take((size_t)NB * 4);
    float* bufA   = (float*)take((size_t)N * 64 * 4);
    float* bufB   = (float*)take((size_t)N * 64 * 4);

    const int* e_src = ei;
    const int* e_dst = ei + E;

    hipMemsetAsync(cnt, 0, (size_t)N * 4, stream);
    k_hist<<<(E + 255) / 256, 256, 0, stream>>>(e_dst, cnt, E);
    k_scan1<<<NB, 1024, 0, stream>>>(cnt, rowptr, bsum, N);
    k_scan2<<<1, 128, 0, stream>>>(bsum, boffs, rowptr, NB, N);
    k_scan3<<<NB, 1024, 0, stream>>>(cnt, rowptr, boffs, cur, dinv, N);
    k_scatter<<<(E + 255) / 256, 256, 0, stream>>>(e_src, e_dst, cur, ssort, E);

    k_transform<<<2048, 256, 0, stream>>>(x, W1, dinv, bufA, N);
    k_agg<<<(N + 3) / 4, 256, 0, stream>>>(bufA, rowptr, ssort, dinv, b1, bufB, N);
    k_transform<<<2048, 256, 0, stream>>>(bufB, W2, dinv, bufA, N);
    k_agg<<<(N + 3) / 4, 256, 0, stream>>>(bufA, rowptr, ssort, dinv, b2, bufB, N);
    k_fc_softmax<<<(N * 16 + 255) / 256, 256, 0, stream>>>(bufB, Wfc, bfc, out, N);
}

// Round 2
// 521.183 us; speedup vs baseline: 1.1985x; 1.1985x over previous
//
#include <hip/hip_runtime.h>
#include <math.h>

#define NNODES 100000

// ---------- CSR build ----------

__global__ __launch_bounds__(256) void k_hist(const int* __restrict__ dst, int* __restrict__ cnt, int E) {
    int i = blockIdx.x * blockDim.x + threadIdx.x;
    int i4 = i * 4;
    if (i4 + 3 < E) {
        int4 d = *(const int4*)(dst + i4);
        atomicAdd(&cnt[d.x], 1);
        atomicAdd(&cnt[d.y], 1);
        atomicAdd(&cnt[d.z], 1);
        atomicAdd(&cnt[d.w], 1);
    } else {
        for (int k = i4; k < E; k++) atomicAdd(&cnt[dst[k]], 1);
    }
}

__global__ __launch_bounds__(1024) void k_scan1(const int* __restrict__ cnt, int* __restrict__ rowptr,
                                                int* __restrict__ bsum, int N) {
    __shared__ int s[1024];
    int t = threadIdx.x;
    int i = blockIdx.x * 1024 + t;
    int v = (i < N) ? cnt[i] : 0;
    s[t] = v;
    __syncthreads();
    #pragma unroll
    for (int off = 1; off < 1024; off <<= 1) {
        int u = (t >= off) ? s[t - off] : 0;
        __syncthreads();
        s[t] += u;
        __syncthreads();
    }
    if (i < N) rowptr[i] = s[t] - v;   // local exclusive prefix
    if (t == 1023) bsum[blockIdx.x] = s[1023];
}

__global__ __launch_bounds__(128) void k_scan2(const int* __restrict__ bsum, int* __restrict__ boffs,
                                               int* __restrict__ rowptr, int nb, int N) {
    __shared__ int s[128];
    int t = threadIdx.x;
    int v = (t < nb) ? bsum[t] : 0;
    s[t] = v;
    __syncthreads();
    #pragma unroll
    for (int off = 1; off < 128; off <<= 1) {
        int u = (t >= off) ? s[t - off] : 0;
        __syncthreads();
        s[t] += u;
        __syncthreads();
    }
    if (t < nb) boffs[t] = s[t] - v;   // exclusive block offsets
    if (t == 127) rowptr[N] = s[127];  // total = E
}

__global__ __launch_bounds__(1024) void k_scan3(const int* __restrict__ cnt, int* __restrict__ rowptr,
                                                const int* __restrict__ boffs, int* __restrict__ cur,
                                                float* __restrict__ dinv, int N) {
    int i = blockIdx.x * 1024 + threadIdx.x;
    if (i >= N) return;
    int val = rowptr[i] + boffs[blockIdx.x];
    rowptr[i] = val;
    cur[i] = val;
    dinv[i] = 1.0f / sqrtf((float)(cnt[i] + 1));  // self-loop included; deg >= 1 always
}

__global__ __launch_bounds__(256) void k_scatter(const int* __restrict__ src, const int* __restrict__ dst,
                                                 int* __restrict__ cur, int* __restrict__ ssort, int E) {
    int i = blockIdx.x * blockDim.x + threadIdx.x;
    int i4 = i * 4;
    if (i4 + 3 < E) {
        int4 s = *(const int4*)(src + i4);
        int4 d = *(const int4*)(dst + i4);
        int p0 = atomicAdd(&cur[d.x], 1);
        int p1 = atomicAdd(&cur[d.y], 1);
        int p2 = atomicAdd(&cur[d.z], 1);
        int p3 = atomicAdd(&cur[d.w], 1);
        ssort[p0] = s.x;
        ssort[p1] = s.y;
        ssort[p2] = s.z;
        ssort[p3] = s.w;
    } else {
        for (int k = i4; k < E; k++) {
            int pos = atomicAdd(&cur[dst[k]], 1);
            ssort[pos] = src[k];
        }
    }
}

// ---------- G = dinv[i] * (X @ W) ----------
// wave-per-node: lane c holds W[:,c] in 64 VGPRs, x row read as uniform float4 broadcasts
__global__ __launch_bounds__(256) void k_transform(const float* __restrict__ X, const float* __restrict__ W,
                                                   const float* __restrict__ dinv, float* __restrict__ G, int N) {
    int lane = threadIdx.x & 63;
    int wid = threadIdx.x >> 6;
    float w[64];
    #pragma unroll
    for (int k = 0; k < 64; k++) w[k] = W[k * 64 + lane];
    int wave = blockIdx.x * 4 + wid;
    int nw = gridDim.x * 4;
    for (int i = wave; i < N; i += nw) {
        const float4* xr = (const float4*)(X + (size_t)i * 64);
        float a0 = 0.f, a1 = 0.f, a2 = 0.f, a3 = 0.f;  // 4 independent FMA chains
        #pragma unroll
        for (int kk = 0; kk < 16; kk++) {
            float4 x4 = xr[kk];
            a0 = fmaf(x4.x, w[4 * kk + 0], a0);
            a1 = fmaf(x4.y, w[4 * kk + 1], a1);
            a2 = fmaf(x4.z, w[4 * kk + 2], a2);
            a3 = fmaf(x4.w, w[4 * kk + 3], a3);
        }
        G[(size_t)i * 64 + lane] = ((a0 + a1) + (a2 + a3)) * dinv[i];
    }
}

// ---------- out = relu(dinv[i] * (G[i] + sum_{j in N(i)} G[j]) + b) ----------
// wave per node; lane = 16*sub + l: sub picks 1 of 4 concurrent edges,
// l picks a float4 feature quarter (16 lanes x 16B = full 256B row, coalesced).
__global__ __launch_bounds__(256) void k_agg(const float* __restrict__ G, const int* __restrict__ rowptr,
                                             const int* __restrict__ ssort, const float* __restrict__ dinv,
                                             const float* __restrict__ bias, float* __restrict__ O, int N) {
    int lane = threadIdx.x & 63;
    int wid = threadIdx.x >> 6;
    int sub = lane >> 4;
    int l = lane & 15;
    int i = blockIdx.x * 4 + wid;
    if (i >= N) return;
    int beg = rowptr[i], end = rowptr[i + 1];
    float ax = 0.f, ay = 0.f, az = 0.f, aw = 0.f;
    int e = beg + sub;
    // 8 edges in flight per iteration (2 per sub)
    for (; e + 4 < end; e += 8) {
        int sA = ssort[e];
        int sB = ssort[e + 4];
        float4 gA = *(const float4*)(G + (size_t)sA * 64 + 4 * l);
        float4 gB = *(const float4*)(G + (size_t)sB * 64 + 4 * l);
        ax += gA.x + gB.x;
        ay += gA.y + gB.y;
        az += gA.z + gB.z;
        aw += gA.w + gB.w;
    }
    if (e < end) {
        int sA = ssort[e];
        float4 gA = *(const float4*)(G + (size_t)sA * 64 + 4 * l);
        ax += gA.x; ay += gA.y; az += gA.z; aw += gA.w;
    }
    // reduce the 4 sub-groups (lanes l, l+16, l+32, l+48 hold partials of the same features)
    #pragma unroll
    for (int mask = 16; mask <= 32; mask <<= 1) {
        ax += __shfl_xor(ax, mask);
        ay += __shfl_xor(ay, mask);
        az += __shfl_xor(az, mask);
        aw += __shfl_xor(aw, mask);
    }
    // self-loop term + epilogue
    float4 gs = *(const float4*)(G + (size_t)i * 64 + 4 * l);
    float4 b4 = *(const float4*)(bias + 4 * l);
    float di = dinv[i];
    if (sub == 0) {
        float4 r;
        r.x = fmaxf(fmaf(di, ax + gs.x, b4.x), 0.f);
        r.y = fmaxf(fmaf(di, ay + gs.y, b4.y), 0.f);
        r.z = fmaxf(fmaf(di, az + gs.z, b4.z), 0.f);
        r.w = fmaxf(fmaf(di, aw + gs.w, b4.w), 0.f);
        *(float4*)(O + (size_t)i * 64 + 4 * l) = r;
    }
}

// ---------- softmax(H @ Wfc + bfc) ----------
__global__ __launch_bounds__(256) void k_fc_softmax(const float* __restrict__ H, const float* __restrict__ Wfc,
                                                    const float* __restrict__ bfc, float* __restrict__ O, int N) {
    __shared__ float wf[64 * 16];
    __shared__ float bf[16];
    int t = threadIdx.x;
    for (int k = t; k < 1024; k += 256) wf[k] = Wfc[k];
    if (t < 16) bf[t] = bfc[t];
    __syncthreads();
    int gid = blockIdx.x * 256 + t;
    int node = gid >> 4;
    int c = gid & 15;
    if (node >= N) return;
    const float4* hv = (const float4*)(H + (size_t)node * 64);
    float acc = bf[c];
    #pragma unroll
    for (int kk = 0; kk < 16; kk++) {
        float4 h4 = hv[kk];
        acc = fmaf(h4.x, wf[(4 * kk + 0) * 16 + c], acc);
        acc = fmaf(h4.y, wf[(4 * kk + 1) * 16 + c], acc);
        acc = fmaf(h4.z, wf[(4 * kk + 2) * 16 + c], acc);
        acc = fmaf(h4.w, wf[(4 * kk + 3) * 16 + c], acc);
    }
    float m = acc;
    #pragma unroll
    for (int mask = 1; mask < 16; mask <<= 1) m = fmaxf(m, __shfl_xor(m, mask));
    float ex = expf(acc - m);
    float s = ex;
    #pragma unroll
    for (int mask = 1; mask < 16; mask <<= 1) s += __shfl_xor(s, mask);
    O[(size_t)node * 16 + c] = ex / s;
}

extern "C" void kernel_launch(void* const* d_in, const int* in_sizes, int n_in,
                              void* d_out, int out_size, void* d_ws, size_t ws_size,
                              hipStream_t stream) {
    const float* x   = (const float*)d_in[0];
    const int*   ei  = (const int*)d_in[1];
    const float* W1  = (const float*)d_in[2];
    const float* b1  = (const float*)d_in[3];
    const float* W2  = (const float*)d_in[4];
    const float* b2  = (const float*)d_in[5];
    const float* Wfc = (const float*)d_in[6];
    const float* bfc = (const float*)d_in[7];
    float* out = (float*)d_out;
    const int N = NNODES;
    const int E = in_sizes[1] / 2;
    const int NB = (N + 1023) / 1024;  // 98

    char* ws = (char*)d_ws;
    size_t off = 0;
    auto take = [&](size_t bytes) {
        char* p = ws + off;
        off = (off + bytes + 255) & ~(size_t)255;
        return p;
    };
    int*   cnt    = (int*)take((size_t)N * 4);
    int*   rowptr = (int*)take((size_t)(N + 1) * 4);
    int*   cur    = (int*)take((size_t)N * 4);
    int*   ssort  = (int*)take((size_t)E * 4);
    float* dinv   = (float*)take((size_t)N * 4);
    int*   bsum   = (int*)take((size_t)NB * 4);
    int*   boffs  = (int*)take((size_t)NB * 4);
    float* bufA   = (float*)take((size_t)N * 64 * 4);
    float* bufB   = (float*)take((size_t)N * 64 * 4);

    const int* e_src = ei;
    const int* e_dst = ei + E;

    hipMemsetAsync(cnt, 0, (size_t)N * 4, stream);
    int ET = (E + 3) / 4;  // threads for 4-edges-per-thread kernels
    k_hist<<<(ET + 255) / 256, 256, 0, stream>>>(e_dst, cnt, E);
    k_scan1<<<NB, 1024, 0, stream>>>(cnt, rowptr, bsum, N);
    k_scan2<<<1, 128, 0, stream>>>(bsum, boffs, rowptr, NB, N);
    k_scan3<<<NB, 1024, 0, stream>>>(cnt, rowptr, boffs, cur, dinv, N);
    k_scatter<<<(ET + 255) / 256, 256, 0, stream>>>(e_src, e_dst, cur, ssort, E);

    k_transform<<<2048, 256, 0, stream>>>(x, W1, dinv, bufA, N);
    k_agg<<<(N + 3) / 4, 256, 0, stream>>>(bufA, rowptr, ssort, dinv, b1, bufB, N);
    k_transform<<<2048, 256, 0, stream>>>(bufB, W2, dinv, bufA, N);
    k_agg<<<(N + 3) / 4, 256, 0, stream>>>(bufA, rowptr, ssort, dinv, b2, bufB, N);
    k_fc_softmax<<<(N * 16 + 255) / 256, 256, 0, stream>>>(bufB, Wfc, bfc, out, N);
}